// Round 1
// 142.878 us; speedup vs baseline: 1.1913x; 1.1913x over previous
//
#include <hip/hip_runtime.h>

#define HW 224
#define HW2 50176            // 224*224
#define NCH 64
#define NPIX (4 * HW2)       // 200704 pixels total
#define CONV_OUT_ELEMS (4 * NCH * HW2)
#define ZCAP 8192            // max recorded exact-zero x elements

typedef short bf16x8 __attribute__((ext_vector_type(8)));
typedef float f32x4 __attribute__((ext_vector_type(4)));

// fp32 -> bf16 round-to-nearest-even
__device__ __forceinline__ unsigned short f2bf(float f) {
    unsigned u = __float_as_uint(f);
    u += 0x7FFFu + ((u >> 16) & 1u);
    return (unsigned short)(u >> 16);
}

// ===========================================================================
// MAIN PATH
// ===========================================================================

// Fused prep: blocks [0,6272) do x NCHW fp32 -> NHWC bf16 (+ exact-zero
// detection for the histogram); blocks [6272,6416) do weight prep.
//
// Weight prep: A-frag lane-major bf16. wbufA elem offset:
//   o = (k*4 + mg)*512 + lane*8 + j,  lane = n + 16q
//   value = w[co = mg*16+n][ci = (k&1)*32 + q*8 + j][tap = k>>1]
__global__ __launch_bounds__(256) void prep_fused(
    const float* __restrict__ xf, const float* __restrict__ w,
    unsigned short* __restrict__ xbf, unsigned short* __restrict__ wbufA,
    int* __restrict__ zcnt, unsigned int* __restrict__ zlist)
{
    const int tid = threadIdx.x;
    const int bid = blockIdx.x;

    if (bid >= 6272) {                      // ---- weight prep ----
        const int o = (bid - 6272) * 256 + tid;
        if (o < 18 * 2048) {                // 36864 elems
            const int j    = o & 7;
            const int lane = (o >> 3) & 63;
            const int n    = lane & 15;
            const int q    = lane >> 4;
            const int mg   = (o >> 9) & 3;
            const int k    = o >> 11;       // 0..17
            const int tap  = k >> 1;
            const int half = k & 1;
            const int ci   = half * 32 + q * 8 + j;
            const int co   = mg * 16 + n;
            wbufA[o] = f2bf(w[(co * 64 + ci) * 9 + tap]);
        }
        return;
    }

    // ---- x prep: thread = (pixel, ci-octet) ----
    const int pix = bid * 32 + (tid >> 3);
    const int oct = tid & 7;
    const int b   = pix / HW2;
    const int rem = pix - b * HW2;
    const float* src = xf + (size_t)(b * NCH + oct * 8) * HW2 + rem;

    float fv[8];
#pragma unroll
    for (int j = 0; j < 8; ++j) fv[j] = src[(size_t)j * HW2];

    bf16x8 v;
#pragma unroll
    for (int j = 0; j < 8; ++j) v[j] = (short)f2bf(fv[j]);
    *reinterpret_cast<bf16x8*>(xbf + (size_t)pix * 64 + oct * 8) = v;

    // rare path: exact fp32 zeros feed the histogram fixup
    bool anyz = false;
#pragma unroll
    for (int j = 0; j < 8; ++j) anyz |= (fv[j] == 0.0f);
    if (__builtin_expect(anyz, 0)) {
        const int yy = rem / HW;
        const int xx = rem - yy * HW;
#pragma unroll
        for (int j = 0; j < 8; ++j) {
            if (fv[j] == 0.0f) {
                const int idx = atomicAdd(zcnt, 1);
                if (idx < ZCAP) {
                    const int ci = oct * 8 + j;
                    zlist[idx] = ((unsigned)b << 22) | ((unsigned)ci << 16)
                               | ((unsigned)yy << 8) | (unsigned)xx;
                }
            }
        }
    }
}

// Conv v2 (unchanged): implicit GEMM on NHWC bf16 input.
// Block (4 waves): 8 rows x 32 cols x all 64 co, one batch. Whole K (64ci x
// 9tap) from one LDS tile: xs[pos = r*34+c][ci64], stored as 16B blocks with
// XOR swizzle  phys16 = pos*8 + (blk ^ (pos&7)).
__global__ __launch_bounds__(256, 3) void conv_mfma_v2(
    const unsigned short* __restrict__ xbf,
    const unsigned short* __restrict__ wbufA,
    const float* __restrict__ bias, float* __restrict__ y)
{
    __shared__ alignas(16) unsigned short xs[340 * 64];  // 43520 B

    const int tid  = threadIdx.x;
    const int wv   = tid >> 6;
    const int lane = tid & 63;
    const int n    = lane & 15;
    const int q    = lane >> 4;
    const int c0   = blockIdx.x * 32;
    const int r0   = blockIdx.y * 8;
    const int b    = blockIdx.z;

    // ---- stage full halo tile: 340 pos x 8 blk 16B units, pure copies ----
    for (int i = tid; i < 2720; i += 256) {
        const int pos = i >> 3;
        const int blk = i & 7;
        const int rr  = pos / 34;
        const int cc  = pos - rr * 34;
        const int gy  = r0 + rr - 1;
        const int gx  = c0 + cc - 1;
        const int phys = pos * 8 + (blk ^ (pos & 7));
        bf16x8 v = (bf16x8){0, 0, 0, 0, 0, 0, 0, 0};
        if ((unsigned)gy < (unsigned)HW && (unsigned)gx < (unsigned)HW)
            v = *reinterpret_cast<const bf16x8*>(
                xbf + ((size_t)(b * HW + gy) * HW + gx) * 64 + blk * 8);
        *reinterpret_cast<bf16x8*>(xs + phys * 8) = v;
    }
    __syncthreads();

    f32x4 acc[4][4];
#pragma unroll
    for (int mg = 0; mg < 4; ++mg)
#pragma unroll
        for (int g = 0; g < 4; ++g) acc[mg][g] = (f32x4){0.f, 0.f, 0.f, 0.f};

    // ---- K loop: 9 taps x 2 ci-halves, 16 MFMAs each ----
#pragma unroll
    for (int tap = 0; tap < 9; ++tap) {
        const int dh = tap / 3, dw = tap % 3;
#pragma unroll
        for (int half = 0; half < 2; ++half) {
            const int k = tap * 2 + half;
            bf16x8 a[4];
#pragma unroll
            for (int mg = 0; mg < 4; ++mg)
                a[mg] = *reinterpret_cast<const bf16x8*>(
                    wbufA + (k * 4 + mg) * 512 + lane * 8);
#pragma unroll
            for (int g = 0; g < 4; ++g) {
                const int pos = (2 * wv + (g >> 1) + dh) * 34
                              + (g & 1) * 16 + dw + n;
                const int phys = pos * 8 + ((half * 4 + q) ^ (pos & 7));
                const bf16x8 bf =
                    *reinterpret_cast<const bf16x8*>(xs + phys * 8);
#pragma unroll
                for (int mg = 0; mg < 4; ++mg)
                    acc[mg][g] = __builtin_amdgcn_mfma_f32_16x16x32_bf16(
                        a[mg], bf, acc[mg][g], 0, 0, 0);
            }
        }
    }

    // ---- epilogue: C/D col=lane&15 (spatial), row=q*4+reg (co) ----
#pragma unroll
    for (int g = 0; g < 4; ++g) {
        const int row = r0 + 2 * wv + (g >> 1);
        const int col = c0 + (g & 1) * 16 + n;
#pragma unroll
        for (int mg = 0; mg < 4; ++mg) {
#pragma unroll
            for (int rg = 0; rg < 4; ++rg) {
                const int co = mg * 16 + q * 4 + rg;
                y[((size_t)(b * NCH + co) * HW + row) * HW + col] =
                    acc[mg][g][rg] + bias[co];
            }
        }
    }
}

// ===========================================================================
// hist_final: single block. Analytic base histogram per channel (exact,
// including w==0 taps) + exact sparse fixup from the recorded x-zero list.
//   z(b,c,r,s) = #taps k where (input OOB) or (w[c][k]==0) or (x at tap == 0)
// Base assumes the x term is absent; each recorded zero perturbs <=9 output
// pixels, which we recompute exactly from global x (with minimal-entry dedup).
// ===========================================================================
__global__ __launch_bounds__(256) void hist_final(
    const float* __restrict__ x, const float* __restrict__ w,
    const int* __restrict__ zcnt, const unsigned int* __restrict__ zlist,
    float* __restrict__ hist)
{
    __shared__ int lh[640];
    const int tid = threadIdx.x;
    for (int i = tid; i < 640; i += 256) lh[i] = 0;
    __syncthreads();

    if (tid < 64) {                         // ---- analytic base, channel=tid
        const int c = tid;
        float wk[9];
#pragma unroll
        for (int k = 0; k < 9; ++k) wk[k] = w[c * 9 + k];
        int bins[10];
#pragma unroll
        for (int k = 0; k < 10; ++k) bins[k] = 0;
#pragma unroll
        for (int rcat = 0; rcat < 3; ++rcat) {
#pragma unroll
            for (int scat = 0; scat < 3; ++scat) {
                int z = 0;
#pragma unroll
                for (int k = 0; k < 9; ++k) {
                    const int kh = k / 3, kw = k % 3;
                    const bool oob =
                        (rcat == 0 && kh == 0) || (rcat == 2 && kh == 2) ||
                        (scat == 0 && kw == 0) || (scat == 2 && kw == 2);
                    z += (oob || wk[k] == 0.0f) ? 1 : 0;
                }
                const int cnt =
                    4 * (rcat == 1 ? 222 : 1) * (scat == 1 ? 222 : 1);
                bins[z] += cnt;
            }
        }
#pragma unroll
        for (int k = 0; k < 10; ++k) lh[c * 10 + k] = bins[k];
    }
    __syncthreads();

    // ---- sparse fixup: pair = (zero-entry e, tap t) -> output pixel ----
    const int L = min(*zcnt, ZCAP);
    for (int p = tid; p < L * 9; p += 256) {
        const int e = p / 9, t = p - e * 9;
        const unsigned ent = zlist[e];
        const int b  = (int)(ent >> 22);
        const int c  = (int)(ent >> 16) & 63;
        const int zy = (int)(ent >> 8) & 255;
        const int zx = (int)ent & 255;
        const int kh = t / 3, kw = t % 3;
        const int r = zy - kh + 1, s = zx - kw + 1;   // affected output pixel
        if ((unsigned)r >= (unsigned)HW || (unsigned)s >= (unsigned)HW)
            continue;
        // dedup: the minimal entry index targeting (b,c,r,s) owns the fixup
        bool first = true;
        for (int e2 = 0; e2 < e && first; ++e2) {
            const unsigned ent2 = zlist[e2];
            if ((ent2 >> 16) == (ent >> 16)) {        // same (b,c)
                const int y2 = (int)(ent2 >> 8) & 255;
                const int x2 = (int)ent2 & 255;
                if ((unsigned)(y2 - r + 1) < 3u && (unsigned)(x2 - s + 1) < 3u)
                    first = false;
            }
        }
        if (!first) continue;

        // recompute exact z_base (no x-zero term) and z_true at (b,c,r,s)
        const float* plane = x + (size_t)(b * NCH + c) * HW2;
        int zb = 0, zt = 0;
#pragma unroll
        for (int k = 0; k < 9; ++k) {
            const int kh2 = k / 3, kw2 = k % 3;
            const int yy = r + kh2 - 1, xx = s + kw2 - 1;
            const bool oob = (unsigned)yy >= (unsigned)HW ||
                             (unsigned)xx >= (unsigned)HW;
            const bool w0 = (w[c * 9 + k] == 0.0f);
            const bool x0 = !oob && (plane[yy * HW + xx] == 0.0f);
            zb += (oob || w0) ? 1 : 0;
            zt += (oob || w0 || x0) ? 1 : 0;
        }
        if (zb != zt) {
            atomicAdd(&lh[c * 10 + zb], -1);
            atomicAdd(&lh[c * 10 + zt], 1);
        }
    }
    __syncthreads();
    for (int i = tid; i < 640; i += 256) hist[i] = (float)lh[i];
}

// ===========================================================================
// FALLBACK PATH (ws too small for the bf16 NHWC copy): round-2 kernels.
// ===========================================================================
__global__ void prep_weights_fb(const float* __restrict__ w,
                                unsigned short* __restrict__ wbuf) {
    const int o = blockIdx.x * 256 + threadIdx.x;
    if (o >= 2 * 9 * 4 * 16 * 32) return;
    const int ci = o & 31;
    const int t1 = o >> 5;
    const int co = t1 & 15;
    const int t2 = t1 >> 4;
    const int mg = t2 & 3;
    const int t3 = t2 >> 2;
    const int tap = t3 % 9;
    const int chunk = t3 / 9;
    wbuf[o] = f2bf(w[((mg * 16 + co) * 64 + (chunk * 32 + ci)) * 9 + tap]);
}

__global__ __launch_bounds__(256, 2) void conv_mfma_fb(
    const float* __restrict__ x, const unsigned short* __restrict__ wbuf,
    const float* __restrict__ bias, float* __restrict__ y)
{
    __shared__ alignas(16) unsigned short xs[340 * 32];
    const int tid  = threadIdx.x;
    const int wv   = tid >> 6;
    const int lane = tid & 63;
    const int n    = lane & 15;
    const int q    = lane >> 4;
    const int c0   = blockIdx.x * 32;
    const int r0   = blockIdx.y * 8;
    const int b    = blockIdx.z;

    f32x4 acc[4][4];
#pragma unroll
    for (int mg = 0; mg < 4; ++mg)
#pragma unroll
        for (int g = 0; g < 4; ++g) acc[mg][g] = (f32x4){0.f, 0.f, 0.f, 0.f};

    for (int chunk = 0; chunk < 2; ++chunk) {
        if (chunk) __syncthreads();
        const int ci0 = chunk * 32;
        for (int i = tid; i < 1360; i += 256) {
            const int ci8 = i / 340;
            const int pos = i - ci8 * 340;
            const int r   = pos / 34;
            const int c   = pos - r * 34;
            const int gy  = r0 + r - 1;
            const int gx  = c0 + c - 1;
            bf16x8 v;
            if ((unsigned)gy < (unsigned)HW && (unsigned)gx < (unsigned)HW) {
                const float* src =
                    x + ((size_t)(b * NCH + ci0 + ci8 * 8) * HW + gy) * HW + gx;
#pragma unroll
                for (int j = 0; j < 8; ++j) v[j] = (short)f2bf(src[(size_t)j * HW2]);
            } else {
#pragma unroll
                for (int j = 0; j < 8; ++j) v[j] = 0;
            }
            *reinterpret_cast<bf16x8*>(&xs[pos * 32 + ci8 * 8]) = v;
        }
        __syncthreads();

#pragma unroll
        for (int tap = 0; tap < 9; ++tap) {
            const int dh = tap / 3, dw = tap % 3;
            bf16x8 a[4];
#pragma unroll
            for (int mg = 0; mg < 4; ++mg) {
                const unsigned short* ap =
                    wbuf + ((chunk * 9 + tap) * 4 + mg) * 512 + n * 32 + q * 8;
                a[mg] = *reinterpret_cast<const bf16x8*>(ap);
            }
#pragma unroll
            for (int g = 0; g < 4; ++g) {
                const int rl = 2 * wv + (g >> 1) + dh;
                const int cl = (g & 1) * 16 + dw + n;
                const bf16x8 bf =
                    *reinterpret_cast<const bf16x8*>(&xs[(rl * 34 + cl) * 32 + q * 8]);
#pragma unroll
                for (int mg = 0; mg < 4; ++mg)
                    acc[mg][g] = __builtin_amdgcn_mfma_f32_16x16x32_bf16(
                        a[mg], bf, acc[mg][g], 0, 0, 0);
            }
        }
    }

#pragma unroll
    for (int g = 0; g < 4; ++g) {
        const int row = r0 + 2 * wv + (g >> 1);
        const int col = c0 + (g & 1) * 16 + n;
#pragma unroll
        for (int mg = 0; mg < 4; ++mg) {
#pragma unroll
            for (int rg = 0; rg < 4; ++rg) {
                const int co = mg * 16 + q * 4 + rg;
                y[((size_t)(b * NCH + co) * HW + row) * HW + col] =
                    acc[mg][g][rg] + bias[co];
            }
        }
    }
}

// hist_v2 (fallback path only): honest full pass over x.
__global__ __launch_bounds__(256) void hist_v2(
    const float* __restrict__ x, const float* __restrict__ w,
    float* __restrict__ hist)
{
    __shared__ int lh[10];
    const int tid = threadIdx.x;
    const int col = tid;                 // active iff < 224
    const int rg  = blockIdx.x;          // 0..7
    const int c   = blockIdx.y;
    const int b   = blockIdx.z;
    if (tid < 10) lh[tid] = 0;
    __syncthreads();

    int h[10];
#pragma unroll
    for (int k = 0; k < 10; ++k) h[k] = 0;

    if (col < HW) {
        const float* plane = x + (size_t)(b * NCH + c) * HW2;
        float wk[9];
#pragma unroll
        for (int k = 0; k < 9; ++k) wk[k] = w[c * 9 + k];

        const bool vl = col > 0, vr = col < HW - 1;
        const int r0 = rg * 28;
        float u0, u1, u2, m0, m1, m2;
        if (r0 > 0) {
            const float* p = plane + (size_t)(r0 - 1) * HW + col;
            u0 = vl ? p[-1] : 0.f; u1 = p[0]; u2 = vr ? p[1] : 0.f;
        } else { u0 = u1 = u2 = 0.f; }
        {
            const float* p = plane + (size_t)r0 * HW + col;
            m0 = vl ? p[-1] : 0.f; m1 = p[0]; m2 = vr ? p[1] : 0.f;
        }

        for (int r = r0; r < r0 + 28; ++r) {
            float d0, d1, d2;
            if (r + 1 < HW) {
                const float* p = plane + (size_t)(r + 1) * HW + col;
                d0 = vl ? p[-1] : 0.f; d1 = p[0]; d2 = vr ? p[1] : 0.f;
            } else { d0 = d1 = d2 = 0.f; }

            int cnt = 0;
            cnt += (u0 * wk[0] != 0.f); cnt += (u1 * wk[1] != 0.f); cnt += (u2 * wk[2] != 0.f);
            cnt += (m0 * wk[3] != 0.f); cnt += (m1 * wk[4] != 0.f); cnt += (m2 * wk[5] != 0.f);
            cnt += (d0 * wk[6] != 0.f); cnt += (d1 * wk[7] != 0.f); cnt += (d2 * wk[8] != 0.f);
            const int z = 9 - cnt;
#pragma unroll
            for (int k = 0; k < 10; ++k) h[k] += (z == k);
            u0 = m0; u1 = m1; u2 = m2; m0 = d0; m1 = d1; m2 = d2;
        }
    }

#pragma unroll
    for (int k = 0; k < 10; ++k) {
        int v = h[k];
        v += __shfl_xor(v, 32); v += __shfl_xor(v, 16); v += __shfl_xor(v, 8);
        v += __shfl_xor(v, 4);  v += __shfl_xor(v, 2);  v += __shfl_xor(v, 1);
        if ((tid & 63) == 0 && v != 0) atomicAdd(&lh[k], v);
    }
    __syncthreads();
    if (tid < 10 && lh[tid] > 0)
        atomicAdd(&hist[c * 10 + tid], (float)lh[tid]);
}

// ===========================================================================
extern "C" void kernel_launch(void* const* d_in, const int* in_sizes, int n_in,
                              void* d_out, int out_size, void* d_ws, size_t ws_size,
                              hipStream_t stream) {
    const float* x    = (const float*)d_in[0];
    const float* w    = (const float*)d_in[1];
    const float* bias = (const float*)d_in[2];
    float* y    = (float*)d_out;
    float* hist = (float*)d_out + CONV_OUT_ELEMS;

    const size_t XBF_OFF = 73728;                              // wbufA bytes
    const size_t ZC_OFF  = XBF_OFF + (size_t)NPIX * 64 * 2;    // 25,763,840
    const size_t ZL_OFF  = ZC_OFF + 64;                        // 64B-aligned
    const size_t NEED    = ZL_OFF + (size_t)ZCAP * 4;

    if (ws_size >= NEED) {
        unsigned short* wbufA = (unsigned short*)d_ws;          // 73728 B
        unsigned short* xbf   = (unsigned short*)((char*)d_ws + XBF_OFF);
        int* zcnt             = (int*)((char*)d_ws + ZC_OFF);
        unsigned int* zlist   = (unsigned int*)((char*)d_ws + ZL_OFF);

        hipMemsetAsync(zcnt, 0, sizeof(int), stream);
        prep_fused<<<6416, 256, 0, stream>>>(x, w, xbf, wbufA, zcnt, zlist);
        conv_mfma_v2<<<dim3(7, 28, 4), 256, 0, stream>>>(xbf, wbufA, bias, y);
        hist_final<<<1, 256, 0, stream>>>(x, w, zcnt, zlist, hist);
    } else {
        hipMemsetAsync(hist, 0, 64 * 10 * sizeof(float), stream);
        unsigned short* wbuf = (unsigned short*)d_ws;
        prep_weights_fb<<<144, 256, 0, stream>>>(w, wbuf);
        conv_mfma_fb<<<dim3(7, 28, 4), 256, 0, stream>>>(x, wbuf, bias, y);
        hist_v2<<<dim3(8, 64, 4), 256, 0, stream>>>(x, w, hist);
    }
}

// Round 2
// 140.045 us; speedup vs baseline: 1.2154x; 1.0202x over previous
//
#include <hip/hip_runtime.h>

#define HW 224
#define HW2 50176            // 224*224
#define NCH 64
#define NPIX (4 * HW2)       // 200704 pixels total
#define CONV_OUT_ELEMS (4 * NCH * HW2)
#define ZCAP 8192            // max recorded exact-zero x elements

typedef short bf16x8 __attribute__((ext_vector_type(8)));
typedef float f32x4 __attribute__((ext_vector_type(4)));

// fp32 -> bf16 round-to-nearest-even
__device__ __forceinline__ unsigned short f2bf(float f) {
    unsigned u = __float_as_uint(f);
    u += 0x7FFFu + ((u >> 16) & 1u);
    return (unsigned short)(u >> 16);
}

// ===========================================================================
// MAIN PATH
// ===========================================================================

// Weight prep: A-frag lane-major bf16. wbufA elem offset:
//   o = (k*4 + mg)*512 + lane*8 + j,  lane = n + 16q
//   value = w[co = mg*16+n][ci = (k&1)*32 + q*8 + j][tap = k>>1]
// Also zeroes the zero-list counter (runs before conv in stream order).
__global__ __launch_bounds__(256) void prep_weights_v2(
    const float* __restrict__ w, unsigned short* __restrict__ wbufA,
    int* __restrict__ zcnt) {
    const int o = blockIdx.x * 256 + threadIdx.x;
    if (o == 0) *zcnt = 0;
    if (o >= 18 * 2048) return;            // 36864 elems
    const int j    = o & 7;
    const int lane = (o >> 3) & 63;
    const int n    = lane & 15;
    const int q    = lane >> 4;
    const int mg   = (o >> 9) & 3;
    const int k    = o >> 11;              // 0..17
    const int tap  = k >> 1;
    const int half = k & 1;
    const int ci   = half * 32 + q * 8 + j;
    const int co   = mg * 16 + n;
    wbufA[o] = f2bf(w[(co * 64 + ci) * 9 + tap]);
}

// Conv fused: implicit GEMM staging DIRECTLY from fp32 NCHW x (no bf16
// intermediate buffer). Block (4 waves): 8 rows x 32 cols x all 64 co, one
// batch. Whole K (64ci x 9tap) from one LDS tile: xs[pos = r*34+c][ci64],
// stored as 16B blocks with XOR swizzle  phys16 = pos*8 + (oct ^ (pos&7)).
// Staging also records exact fp32 zeros of x (owned region only -> each
// in-bounds element inspected exactly once) for the histogram fixup.
__global__ __launch_bounds__(256, 3) void conv_fused(
    const float* __restrict__ xf,
    const unsigned short* __restrict__ wbufA,
    const float* __restrict__ bias, float* __restrict__ y,
    int* __restrict__ zcnt, unsigned int* __restrict__ zlist)
{
    __shared__ alignas(16) unsigned short xs[340 * 64];  // 43520 B

    const int tid  = threadIdx.x;
    const int wv   = tid >> 6;
    const int lane = tid & 63;
    const int n    = lane & 15;
    const int q    = lane >> 4;
    const int c0   = blockIdx.x * 32;
    const int r0   = blockIdx.y * 8;
    const int b    = blockIdx.z;

    // ---- stage full halo tile from fp32 NCHW: 340 pos x 8 ci-octets ----
    // oct-major: consecutive threads -> consecutive pos -> contiguous gx runs
    for (int i = tid; i < 2720; i += 256) {
        const int oct = i / 340;
        const int pos = i - oct * 340;
        const int rr  = pos / 34;
        const int cc  = pos - rr * 34;
        const int gy  = r0 + rr - 1;
        const int gx  = c0 + cc - 1;
        const int phys = pos * 8 + (oct ^ (pos & 7));
        bf16x8 v = (bf16x8){0, 0, 0, 0, 0, 0, 0, 0};
        if ((unsigned)gy < (unsigned)HW && (unsigned)gx < (unsigned)HW) {
            const float* src =
                xf + ((size_t)(b * NCH + oct * 8) * HW + gy) * HW + gx;
            float fv[8];
#pragma unroll
            for (int j = 0; j < 8; ++j) fv[j] = src[(size_t)j * HW2];
#pragma unroll
            for (int j = 0; j < 8; ++j) v[j] = (short)f2bf(fv[j]);
            // rare path: record exact fp32 zeros, owned region only
            bool anyz = false;
#pragma unroll
            for (int j = 0; j < 8; ++j) anyz |= (fv[j] == 0.0f);
            if (__builtin_expect(anyz, 0) &&
                rr >= 1 && rr <= 8 && cc >= 1 && cc <= 32) {
#pragma unroll
                for (int j = 0; j < 8; ++j) {
                    if (fv[j] == 0.0f) {
                        const int idx = atomicAdd(zcnt, 1);
                        if (idx < ZCAP) {
                            const int ci = oct * 8 + j;
                            zlist[idx] = ((unsigned)b << 22)
                                       | ((unsigned)ci << 16)
                                       | ((unsigned)gy << 8) | (unsigned)gx;
                        }
                    }
                }
            }
        }
        *reinterpret_cast<bf16x8*>(xs + phys * 8) = v;
    }
    __syncthreads();

    f32x4 acc[4][4];
#pragma unroll
    for (int mg = 0; mg < 4; ++mg)
#pragma unroll
        for (int g = 0; g < 4; ++g) acc[mg][g] = (f32x4){0.f, 0.f, 0.f, 0.f};

    // ---- K loop: 9 taps x 2 ci-halves, 16 MFMAs each ----
#pragma unroll
    for (int tap = 0; tap < 9; ++tap) {
        const int dh = tap / 3, dw = tap % 3;
#pragma unroll
        for (int half = 0; half < 2; ++half) {
            const int k = tap * 2 + half;
            bf16x8 a[4];
#pragma unroll
            for (int mg = 0; mg < 4; ++mg)
                a[mg] = *reinterpret_cast<const bf16x8*>(
                    wbufA + (k * 4 + mg) * 512 + lane * 8);
#pragma unroll
            for (int g = 0; g < 4; ++g) {
                const int pos = (2 * wv + (g >> 1) + dh) * 34
                              + (g & 1) * 16 + dw + n;
                const int phys = pos * 8 + ((half * 4 + q) ^ (pos & 7));
                const bf16x8 bf =
                    *reinterpret_cast<const bf16x8*>(xs + phys * 8);
#pragma unroll
                for (int mg = 0; mg < 4; ++mg)
                    acc[mg][g] = __builtin_amdgcn_mfma_f32_16x16x32_bf16(
                        a[mg], bf, acc[mg][g], 0, 0, 0);
            }
        }
    }

    // ---- epilogue: C/D col=lane&15 (spatial), row=q*4+reg (co) ----
#pragma unroll
    for (int g = 0; g < 4; ++g) {
        const int row = r0 + 2 * wv + (g >> 1);
        const int col = c0 + (g & 1) * 16 + n;
#pragma unroll
        for (int mg = 0; mg < 4; ++mg) {
#pragma unroll
            for (int rg = 0; rg < 4; ++rg) {
                const int co = mg * 16 + q * 4 + rg;
                y[((size_t)(b * NCH + co) * HW + row) * HW + col] =
                    acc[mg][g][rg] + bias[co];
            }
        }
    }
}

// ===========================================================================
// hist_final: single block. Analytic base histogram per channel (exact,
// including w==0 taps) + exact sparse fixup from the recorded x-zero list.
//   z(b,c,r,s) = #taps k where (input OOB) or (w[c][k]==0) or (x at tap == 0)
// Base assumes the x term is absent; each recorded zero perturbs <=9 output
// pixels, which we recompute exactly from global x (with minimal-entry dedup).
// ===========================================================================
__global__ __launch_bounds__(256) void hist_final(
    const float* __restrict__ x, const float* __restrict__ w,
    const int* __restrict__ zcnt, const unsigned int* __restrict__ zlist,
    float* __restrict__ hist)
{
    __shared__ int lh[640];
    const int tid = threadIdx.x;
    for (int i = tid; i < 640; i += 256) lh[i] = 0;
    __syncthreads();

    if (tid < 64) {                         // ---- analytic base, channel=tid
        const int c = tid;
        float wk[9];
#pragma unroll
        for (int k = 0; k < 9; ++k) wk[k] = w[c * 9 + k];
        int bins[10];
#pragma unroll
        for (int k = 0; k < 10; ++k) bins[k] = 0;
#pragma unroll
        for (int rcat = 0; rcat < 3; ++rcat) {
#pragma unroll
            for (int scat = 0; scat < 3; ++scat) {
                int z = 0;
#pragma unroll
                for (int k = 0; k < 9; ++k) {
                    const int kh = k / 3, kw = k % 3;
                    const bool oob =
                        (rcat == 0 && kh == 0) || (rcat == 2 && kh == 2) ||
                        (scat == 0 && kw == 0) || (scat == 2 && kw == 2);
                    z += (oob || wk[k] == 0.0f) ? 1 : 0;
                }
                const int cnt =
                    4 * (rcat == 1 ? 222 : 1) * (scat == 1 ? 222 : 1);
                bins[z] += cnt;
            }
        }
#pragma unroll
        for (int k = 0; k < 10; ++k) lh[c * 10 + k] = bins[k];
    }
    __syncthreads();

    // ---- sparse fixup: pair = (zero-entry e, tap t) -> output pixel ----
    const int L = min(*zcnt, ZCAP);
    for (int p = tid; p < L * 9; p += 256) {
        const int e = p / 9, t = p - e * 9;
        const unsigned ent = zlist[e];
        const int b  = (int)(ent >> 22);
        const int c  = (int)(ent >> 16) & 63;
        const int zy = (int)(ent >> 8) & 255;
        const int zx = (int)ent & 255;
        const int kh = t / 3, kw = t % 3;
        const int r = zy - kh + 1, s = zx - kw + 1;   // affected output pixel
        if ((unsigned)r >= (unsigned)HW || (unsigned)s >= (unsigned)HW)
            continue;
        // dedup: the minimal entry index targeting (b,c,r,s) owns the fixup
        bool first = true;
        for (int e2 = 0; e2 < e && first; ++e2) {
            const unsigned ent2 = zlist[e2];
            if ((ent2 >> 16) == (ent >> 16)) {        // same (b,c)
                const int y2 = (int)(ent2 >> 8) & 255;
                const int x2 = (int)ent2 & 255;
                if ((unsigned)(y2 - r + 1) < 3u && (unsigned)(x2 - s + 1) < 3u)
                    first = false;
            }
        }
        if (!first) continue;

        // recompute exact z_base (no x-zero term) and z_true at (b,c,r,s)
        const float* plane = x + (size_t)(b * NCH + c) * HW2;
        int zb = 0, zt = 0;
#pragma unroll
        for (int k = 0; k < 9; ++k) {
            const int kh2 = k / 3, kw2 = k % 3;
            const int yy = r + kh2 - 1, xx = s + kw2 - 1;
            const bool oob = (unsigned)yy >= (unsigned)HW ||
                             (unsigned)xx >= (unsigned)HW;
            const bool w0 = (w[c * 9 + k] == 0.0f);
            const bool x0 = !oob && (plane[yy * HW + xx] == 0.0f);
            zb += (oob || w0) ? 1 : 0;
            zt += (oob || w0 || x0) ? 1 : 0;
        }
        if (zb != zt) {
            atomicAdd(&lh[c * 10 + zb], -1);
            atomicAdd(&lh[c * 10 + zt], 1);
        }
    }
    __syncthreads();
    for (int i = tid; i < 640; i += 256) hist[i] = (float)lh[i];
}

// ===========================================================================
// FALLBACK PATH (ws too small): round-2 kernels.
// ===========================================================================
__global__ void prep_weights_fb(const float* __restrict__ w,
                                unsigned short* __restrict__ wbuf) {
    const int o = blockIdx.x * 256 + threadIdx.x;
    if (o >= 2 * 9 * 4 * 16 * 32) return;
    const int ci = o & 31;
    const int t1 = o >> 5;
    const int co = t1 & 15;
    const int t2 = t1 >> 4;
    const int mg = t2 & 3;
    const int t3 = t2 >> 2;
    const int tap = t3 % 9;
    const int chunk = t3 / 9;
    wbuf[o] = f2bf(w[((mg * 16 + co) * 64 + (chunk * 32 + ci)) * 9 + tap]);
}

__global__ __launch_bounds__(256, 2) void conv_mfma_fb(
    const float* __restrict__ x, const unsigned short* __restrict__ wbuf,
    const float* __restrict__ bias, float* __restrict__ y)
{
    __shared__ alignas(16) unsigned short xs[340 * 32];
    const int tid  = threadIdx.x;
    const int wv   = tid >> 6;
    const int lane = tid & 63;
    const int n    = lane & 15;
    const int q    = lane >> 4;
    const int c0   = blockIdx.x * 32;
    const int r0   = blockIdx.y * 8;
    const int b    = blockIdx.z;

    f32x4 acc[4][4];
#pragma unroll
    for (int mg = 0; mg < 4; ++mg)
#pragma unroll
        for (int g = 0; g < 4; ++g) acc[mg][g] = (f32x4){0.f, 0.f, 0.f, 0.f};

    for (int chunk = 0; chunk < 2; ++chunk) {
        if (chunk) __syncthreads();
        const int ci0 = chunk * 32;
        for (int i = tid; i < 1360; i += 256) {
            const int ci8 = i / 340;
            const int pos = i - ci8 * 340;
            const int r   = pos / 34;
            const int c   = pos - r * 34;
            const int gy  = r0 + r - 1;
            const int gx  = c0 + c - 1;
            bf16x8 v;
            if ((unsigned)gy < (unsigned)HW && (unsigned)gx < (unsigned)HW) {
                const float* src =
                    x + ((size_t)(b * NCH + ci0 + ci8 * 8) * HW + gy) * HW + gx;
#pragma unroll
                for (int j = 0; j < 8; ++j) v[j] = (short)f2bf(src[(size_t)j * HW2]);
            } else {
#pragma unroll
                for (int j = 0; j < 8; ++j) v[j] = 0;
            }
            *reinterpret_cast<bf16x8*>(&xs[pos * 32 + ci8 * 8]) = v;
        }
        __syncthreads();

#pragma unroll
        for (int tap = 0; tap < 9; ++tap) {
            const int dh = tap / 3, dw = tap % 3;
            bf16x8 a[4];
#pragma unroll
            for (int mg = 0; mg < 4; ++mg) {
                const unsigned short* ap =
                    wbuf + ((chunk * 9 + tap) * 4 + mg) * 512 + n * 32 + q * 8;
                a[mg] = *reinterpret_cast<const bf16x8*>(ap);
            }
#pragma unroll
            for (int g = 0; g < 4; ++g) {
                const int rl = 2 * wv + (g >> 1) + dh;
                const int cl = (g & 1) * 16 + dw + n;
                const bf16x8 bf =
                    *reinterpret_cast<const bf16x8*>(&xs[(rl * 34 + cl) * 32 + q * 8]);
#pragma unroll
                for (int mg = 0; mg < 4; ++mg)
                    acc[mg][g] = __builtin_amdgcn_mfma_f32_16x16x32_bf16(
                        a[mg], bf, acc[mg][g], 0, 0, 0);
            }
        }
    }

#pragma unroll
    for (int g = 0; g < 4; ++g) {
        const int row = r0 + 2 * wv + (g >> 1);
        const int col = c0 + (g & 1) * 16 + n;
#pragma unroll
        for (int mg = 0; mg < 4; ++mg) {
#pragma unroll
            for (int rg = 0; rg < 4; ++rg) {
                const int co = mg * 16 + q * 4 + rg;
                y[((size_t)(b * NCH + co) * HW + row) * HW + col] =
                    acc[mg][g][rg] + bias[co];
            }
        }
    }
}

// hist_v2 (fallback path only): honest full pass over x.
__global__ __launch_bounds__(256) void hist_v2(
    const float* __restrict__ x, const float* __restrict__ w,
    float* __restrict__ hist)
{
    __shared__ int lh[10];
    const int tid = threadIdx.x;
    const int col = tid;                 // active iff < 224
    const int rg  = blockIdx.x;          // 0..7
    const int c   = blockIdx.y;
    const int b   = blockIdx.z;
    if (tid < 10) lh[tid] = 0;
    __syncthreads();

    int h[10];
#pragma unroll
    for (int k = 0; k < 10; ++k) h[k] = 0;

    if (col < HW) {
        const float* plane = x + (size_t)(b * NCH + c) * HW2;
        float wk[9];
#pragma unroll
        for (int k = 0; k < 9; ++k) wk[k] = w[c * 9 + k];

        const bool vl = col > 0, vr = col < HW - 1;
        const int r0 = rg * 28;
        float u0, u1, u2, m0, m1, m2;
        if (r0 > 0) {
            const float* p = plane + (size_t)(r0 - 1) * HW + col;
            u0 = vl ? p[-1] : 0.f; u1 = p[0]; u2 = vr ? p[1] : 0.f;
        } else { u0 = u1 = u2 = 0.f; }
        {
            const float* p = plane + (size_t)r0 * HW + col;
            m0 = vl ? p[-1] : 0.f; m1 = p[0]; m2 = vr ? p[1] : 0.f;
        }

        for (int r = r0; r < r0 + 28; ++r) {
            float d0, d1, d2;
            if (r + 1 < HW) {
                const float* p = plane + (size_t)(r + 1) * HW + col;
                d0 = vl ? p[-1] : 0.f; d1 = p[0]; d2 = vr ? p[1] : 0.f;
            } else { d0 = d1 = d2 = 0.f; }

            int cnt = 0;
            cnt += (u0 * wk[0] != 0.f); cnt += (u1 * wk[1] != 0.f); cnt += (u2 * wk[2] != 0.f);
            cnt += (m0 * wk[3] != 0.f); cnt += (m1 * wk[4] != 0.f); cnt += (m2 * wk[5] != 0.f);
            cnt += (d0 * wk[6] != 0.f); cnt += (d1 * wk[7] != 0.f); cnt += (d2 * wk[8] != 0.f);
            const int z = 9 - cnt;
#pragma unroll
            for (int k = 0; k < 10; ++k) h[k] += (z == k);
            u0 = m0; u1 = m1; u2 = m2; m0 = d0; m1 = d1; m2 = d2;
        }
    }

#pragma unroll
    for (int k = 0; k < 10; ++k) {
        int v = h[k];
        v += __shfl_xor(v, 32); v += __shfl_xor(v, 16); v += __shfl_xor(v, 8);
        v += __shfl_xor(v, 4);  v += __shfl_xor(v, 2);  v += __shfl_xor(v, 1);
        if ((tid & 63) == 0 && v != 0) atomicAdd(&lh[k], v);
    }
    __syncthreads();
    if (tid < 10 && lh[tid] > 0)
        atomicAdd(&hist[c * 10 + tid], (float)lh[tid]);
}

// ===========================================================================
extern "C" void kernel_launch(void* const* d_in, const int* in_sizes, int n_in,
                              void* d_out, int out_size, void* d_ws, size_t ws_size,
                              hipStream_t stream) {
    const float* x    = (const float*)d_in[0];
    const float* w    = (const float*)d_in[1];
    const float* bias = (const float*)d_in[2];
    float* y    = (float*)d_out;
    float* hist = (float*)d_out + CONV_OUT_ELEMS;

    const size_t ZC_OFF = 73728;               // after wbufA (64B-aligned)
    const size_t ZL_OFF = ZC_OFF + 64;
    const size_t NEED   = ZL_OFF + (size_t)ZCAP * 4;   // ~106 KB

    if (ws_size >= NEED) {
        unsigned short* wbufA = (unsigned short*)d_ws;          // 73728 B
        int* zcnt             = (int*)((char*)d_ws + ZC_OFF);
        unsigned int* zlist   = (unsigned int*)((char*)d_ws + ZL_OFF);

        prep_weights_v2<<<144, 256, 0, stream>>>(w, wbufA, zcnt);
        conv_fused<<<dim3(7, 28, 4), 256, 0, stream>>>(
            x, wbufA, bias, y, zcnt, zlist);
        hist_final<<<1, 256, 0, stream>>>(x, w, zcnt, zlist, hist);
    } else {
        hipMemsetAsync(hist, 0, 64 * 10 * sizeof(float), stream);
        unsigned short* wbuf = (unsigned short*)d_ws;
        prep_weights_fb<<<144, 256, 0, stream>>>(w, wbuf);
        conv_mfma_fb<<<dim3(7, 28, 4), 256, 0, stream>>>(x, wbuf, bias, y);
        hist_v2<<<dim3(8, 64, 4), 256, 0, stream>>>(x, w, hist);
    }
}

// Round 3
// 131.806 us; speedup vs baseline: 1.2914x; 1.0625x over previous
//
#include <hip/hip_runtime.h>

#define HW 224
#define HW2 50176            // 224*224
#define NCH 64
#define NPIX (4 * HW2)       // 200704 pixels total
#define CONV_OUT_ELEMS (4 * NCH * HW2)
#define ZCAP 8192            // max recorded exact-zero x elements

typedef short bf16x8 __attribute__((ext_vector_type(8)));
typedef float f32x4 __attribute__((ext_vector_type(4)));

// fp32 -> bf16 round-to-nearest-even
__device__ __forceinline__ unsigned short f2bf(float f) {
    unsigned u = __float_as_uint(f);
    u += 0x7FFFu + ((u >> 16) & 1u);
    return (unsigned short)(u >> 16);
}

// ===========================================================================
// MAIN PATH
// ===========================================================================

// Weight prep: A-frag lane-major bf16. wbufA elem offset:
//   o = (k*4 + mg)*512 + lane*8 + j,  lane = n + 16q
//   value = w[co = mg*16+n][ci = (k&1)*32 + q*8 + j][tap = k>>1]
// Also zeroes the zero-list counter (runs before conv in stream order).
__global__ __launch_bounds__(256) void prep_weights_v2(
    const float* __restrict__ w, unsigned short* __restrict__ wbufA,
    int* __restrict__ zcnt) {
    const int o = blockIdx.x * 256 + threadIdx.x;
    if (o == 0) *zcnt = 0;
    if (o >= 18 * 2048) return;            // 36864 elems
    const int j    = o & 7;
    const int lane = (o >> 3) & 63;
    const int n    = lane & 15;
    const int q    = lane >> 4;
    const int mg   = (o >> 9) & 3;
    const int k    = o >> 11;              // 0..17
    const int tap  = k >> 1;
    const int half = k & 1;
    const int ci   = half * 32 + q * 8 + j;
    const int co   = mg * 16 + n;
    wbufA[o] = f2bf(w[(co * 64 + ci) * 9 + tap]);
}

// Conv fused: implicit GEMM staging DIRECTLY from fp32 NCHW x.
// Staging is two-phase (T14 issue-early/consume-late): phase 1 issues ALL 88
// dword loads per thread unconditionally (clamped addresses, no control flow
// between loads -> ~22 KB in flight per wave, BW-bound); phase 2 recomputes
// geometry, selects 0 for OOB, converts to bf16, writes LDS (XOR-swizzled),
// and scans for exact fp32 zeros (owned region only) for the histogram fixup.
__global__ __launch_bounds__(256, 3) void conv_fused(
    const float* __restrict__ xf,
    const unsigned short* __restrict__ wbufA,
    const float* __restrict__ bias, float* __restrict__ y,
    int* __restrict__ zcnt, unsigned int* __restrict__ zlist)
{
    __shared__ alignas(16) unsigned short xs[340 * 64];  // 43520 B

    const int tid  = threadIdx.x;
    const int wv   = tid >> 6;
    const int lane = tid & 63;
    const int n    = lane & 15;
    const int q    = lane >> 4;
    const int c0   = blockIdx.x * 32;
    const int r0   = blockIdx.y * 8;
    const int b    = blockIdx.z;

    // ---- phase 1: issue all staging loads (clamped, unconditional) ----
    float fv[11][8];
#pragma unroll
    for (int it = 0; it < 11; ++it) {
        const int i   = tid + it * 256;
        const int ii  = i < 2720 ? i : 2719;
        const int oct = ii / 340;
        const int pos = ii - oct * 340;
        const int rr  = pos / 34;
        const int cc  = pos - rr * 34;
        const int gy  = r0 + rr - 1;
        const int gx  = c0 + cc - 1;
        const int cgy = min(max(gy, 0), HW - 1);
        const int cgx = min(max(gx, 0), HW - 1);
        const float* p =
            xf + ((size_t)(b * NCH + oct * 8) * HW + cgy) * HW + cgx;
#pragma unroll
        for (int j = 0; j < 8; ++j) fv[it][j] = p[(size_t)j * HW2];
    }
    __builtin_amdgcn_sched_barrier(0);   // keep all loads above the consumers

    // ---- phase 2: convert, write LDS, zero-scan ----
#pragma unroll
    for (int it = 0; it < 11; ++it) {
        const int i = tid + it * 256;
        if (i < 2720) {
            const int oct = i / 340;
            const int pos = i - oct * 340;
            const int rr  = pos / 34;
            const int cc  = pos - rr * 34;
            const int gy  = r0 + rr - 1;
            const int gx  = c0 + cc - 1;
            const bool inb =
                (unsigned)gy < (unsigned)HW && (unsigned)gx < (unsigned)HW;
            bf16x8 v;
            bool anyz = false;
#pragma unroll
            for (int j = 0; j < 8; ++j) {
                const float f = inb ? fv[it][j] : 0.0f;
                v[j] = (short)f2bf(f);
                anyz |= (f == 0.0f);
            }
            const int phys = pos * 8 + (oct ^ (pos & 7));
            *reinterpret_cast<bf16x8*>(xs + phys * 8) = v;
            // rare path: record exact zeros; owned region is always in-bounds
            if (__builtin_expect(
                    anyz && rr >= 1 && rr <= 8 && cc >= 1 && cc <= 32, 0)) {
#pragma unroll
                for (int j = 0; j < 8; ++j) {
                    if (fv[it][j] == 0.0f) {
                        const int idx = atomicAdd(zcnt, 1);
                        if (idx < ZCAP) {
                            const int ci = oct * 8 + j;
                            zlist[idx] = ((unsigned)b << 22)
                                       | ((unsigned)ci << 16)
                                       | ((unsigned)gy << 8) | (unsigned)gx;
                        }
                    }
                }
            }
        }
    }
    __syncthreads();

    f32x4 acc[4][4];
#pragma unroll
    for (int mg = 0; mg < 4; ++mg)
#pragma unroll
        for (int g = 0; g < 4; ++g) acc[mg][g] = (f32x4){0.f, 0.f, 0.f, 0.f};

    // ---- K loop: 9 taps x 2 ci-halves, 16 MFMAs each ----
#pragma unroll
    for (int tap = 0; tap < 9; ++tap) {
        const int dh = tap / 3, dw = tap % 3;
#pragma unroll
        for (int half = 0; half < 2; ++half) {
            const int k = tap * 2 + half;
            bf16x8 a[4];
#pragma unroll
            for (int mg = 0; mg < 4; ++mg)
                a[mg] = *reinterpret_cast<const bf16x8*>(
                    wbufA + (k * 4 + mg) * 512 + lane * 8);
#pragma unroll
            for (int g = 0; g < 4; ++g) {
                const int pos = (2 * wv + (g >> 1) + dh) * 34
                              + (g & 1) * 16 + dw + n;
                const int phys = pos * 8 + ((half * 4 + q) ^ (pos & 7));
                const bf16x8 bf =
                    *reinterpret_cast<const bf16x8*>(xs + phys * 8);
#pragma unroll
                for (int mg = 0; mg < 4; ++mg)
                    acc[mg][g] = __builtin_amdgcn_mfma_f32_16x16x32_bf16(
                        a[mg], bf, acc[mg][g], 0, 0, 0);
            }
        }
    }

    // ---- epilogue: C/D col=lane&15 (spatial), row=q*4+reg (co) ----
#pragma unroll
    for (int g = 0; g < 4; ++g) {
        const int row = r0 + 2 * wv + (g >> 1);
        const int col = c0 + (g & 1) * 16 + n;
#pragma unroll
        for (int mg = 0; mg < 4; ++mg) {
#pragma unroll
            for (int rg = 0; rg < 4; ++rg) {
                const int co = mg * 16 + q * 4 + rg;
                y[((size_t)(b * NCH + co) * HW + row) * HW + col] =
                    acc[mg][g][rg] + bias[co];
            }
        }
    }
}

// ===========================================================================
// hist_final: single block. Analytic base histogram per channel (exact,
// including w==0 taps) + exact sparse fixup from the recorded x-zero list.
//   z(b,c,r,s) = #taps k where (input OOB) or (w[c][k]==0) or (x at tap == 0)
// Base assumes the x term is absent; each recorded zero perturbs <=9 output
// pixels, which we recompute exactly from global x (with minimal-entry dedup).
// ===========================================================================
__global__ __launch_bounds__(256) void hist_final(
    const float* __restrict__ x, const float* __restrict__ w,
    const int* __restrict__ zcnt, const unsigned int* __restrict__ zlist,
    float* __restrict__ hist)
{
    __shared__ int lh[640];
    const int tid = threadIdx.x;
    for (int i = tid; i < 640; i += 256) lh[i] = 0;
    __syncthreads();

    if (tid < 64) {                         // ---- analytic base, channel=tid
        const int c = tid;
        float wk[9];
#pragma unroll
        for (int k = 0; k < 9; ++k) wk[k] = w[c * 9 + k];
        int bins[10];
#pragma unroll
        for (int k = 0; k < 10; ++k) bins[k] = 0;
#pragma unroll
        for (int rcat = 0; rcat < 3; ++rcat) {
#pragma unroll
            for (int scat = 0; scat < 3; ++scat) {
                int z = 0;
#pragma unroll
                for (int k = 0; k < 9; ++k) {
                    const int kh = k / 3, kw = k % 3;
                    const bool oob =
                        (rcat == 0 && kh == 0) || (rcat == 2 && kh == 2) ||
                        (scat == 0 && kw == 0) || (scat == 2 && kw == 2);
                    z += (oob || wk[k] == 0.0f) ? 1 : 0;
                }
                const int cnt =
                    4 * (rcat == 1 ? 222 : 1) * (scat == 1 ? 222 : 1);
                bins[z] += cnt;
            }
        }
#pragma unroll
        for (int k = 0; k < 10; ++k) lh[c * 10 + k] = bins[k];
    }
    __syncthreads();

    // ---- sparse fixup: pair = (zero-entry e, tap t) -> output pixel ----
    const int L = min(*zcnt, ZCAP);
    for (int p = tid; p < L * 9; p += 256) {
        const int e = p / 9, t = p - e * 9;
        const unsigned ent = zlist[e];
        const int b  = (int)(ent >> 22);
        const int c  = (int)(ent >> 16) & 63;
        const int zy = (int)(ent >> 8) & 255;
        const int zx = (int)ent & 255;
        const int kh = t / 3, kw = t % 3;
        const int r = zy - kh + 1, s = zx - kw + 1;   // affected output pixel
        if ((unsigned)r >= (unsigned)HW || (unsigned)s >= (unsigned)HW)
            continue;
        // dedup: the minimal entry index targeting (b,c,r,s) owns the fixup
        bool first = true;
        for (int e2 = 0; e2 < e && first; ++e2) {
            const unsigned ent2 = zlist[e2];
            if ((ent2 >> 16) == (ent >> 16)) {        // same (b,c)
                const int y2 = (int)(ent2 >> 8) & 255;
                const int x2 = (int)ent2 & 255;
                if ((unsigned)(y2 - r + 1) < 3u && (unsigned)(x2 - s + 1) < 3u)
                    first = false;
            }
        }
        if (!first) continue;

        // recompute exact z_base (no x-zero term) and z_true at (b,c,r,s)
        const float* plane = x + (size_t)(b * NCH + c) * HW2;
        int zb = 0, zt = 0;
#pragma unroll
        for (int k = 0; k < 9; ++k) {
            const int kh2 = k / 3, kw2 = k % 3;
            const int yy = r + kh2 - 1, xx = s + kw2 - 1;
            const bool oob = (unsigned)yy >= (unsigned)HW ||
                             (unsigned)xx >= (unsigned)HW;
            const bool w0 = (w[c * 9 + k] == 0.0f);
            const bool x0 = !oob && (plane[yy * HW + xx] == 0.0f);
            zb += (oob || w0) ? 1 : 0;
            zt += (oob || w0 || x0) ? 1 : 0;
        }
        if (zb != zt) {
            atomicAdd(&lh[c * 10 + zb], -1);
            atomicAdd(&lh[c * 10 + zt], 1);
        }
    }
    __syncthreads();
    for (int i = tid; i < 640; i += 256) hist[i] = (float)lh[i];
}

// ===========================================================================
// FALLBACK PATH (ws too small): round-2 kernels.
// ===========================================================================
__global__ void prep_weights_fb(const float* __restrict__ w,
                                unsigned short* __restrict__ wbuf) {
    const int o = blockIdx.x * 256 + threadIdx.x;
    if (o >= 2 * 9 * 4 * 16 * 32) return;
    const int ci = o & 31;
    const int t1 = o >> 5;
    const int co = t1 & 15;
    const int t2 = t1 >> 4;
    const int mg = t2 & 3;
    const int t3 = t2 >> 2;
    const int tap = t3 % 9;
    const int chunk = t3 / 9;
    wbuf[o] = f2bf(w[((mg * 16 + co) * 64 + (chunk * 32 + ci)) * 9 + tap]);
}

__global__ __launch_bounds__(256, 2) void conv_mfma_fb(
    const float* __restrict__ x, const unsigned short* __restrict__ wbuf,
    const float* __restrict__ bias, float* __restrict__ y)
{
    __shared__ alignas(16) unsigned short xs[340 * 32];
    const int tid  = threadIdx.x;
    const int wv   = tid >> 6;
    const int lane = tid & 63;
    const int n    = lane & 15;
    const int q    = lane >> 4;
    const int c0   = blockIdx.x * 32;
    const int r0   = blockIdx.y * 8;
    const int b    = blockIdx.z;

    f32x4 acc[4][4];
#pragma unroll
    for (int mg = 0; mg < 4; ++mg)
#pragma unroll
        for (int g = 0; g < 4; ++g) acc[mg][g] = (f32x4){0.f, 0.f, 0.f, 0.f};

    for (int chunk = 0; chunk < 2; ++chunk) {
        if (chunk) __syncthreads();
        const int ci0 = chunk * 32;
        for (int i = tid; i < 1360; i += 256) {
            const int ci8 = i / 340;
            const int pos = i - ci8 * 340;
            const int r   = pos / 34;
            const int c   = pos - r * 34;
            const int gy  = r0 + r - 1;
            const int gx  = c0 + c - 1;
            bf16x8 v;
            if ((unsigned)gy < (unsigned)HW && (unsigned)gx < (unsigned)HW) {
                const float* src =
                    x + ((size_t)(b * NCH + ci0 + ci8 * 8) * HW + gy) * HW + gx;
#pragma unroll
                for (int j = 0; j < 8; ++j) v[j] = (short)f2bf(src[(size_t)j * HW2]);
            } else {
#pragma unroll
                for (int j = 0; j < 8; ++j) v[j] = 0;
            }
            *reinterpret_cast<bf16x8*>(&xs[pos * 32 + ci8 * 8]) = v;
        }
        __syncthreads();

#pragma unroll
        for (int tap = 0; tap < 9; ++tap) {
            const int dh = tap / 3, dw = tap % 3;
            bf16x8 a[4];
#pragma unroll
            for (int mg = 0; mg < 4; ++mg) {
                const unsigned short* ap =
                    wbuf + ((chunk * 9 + tap) * 4 + mg) * 512 + n * 32 + q * 8;
                a[mg] = *reinterpret_cast<const bf16x8*>(ap);
            }
#pragma unroll
            for (int g = 0; g < 4; ++g) {
                const int rl = 2 * wv + (g >> 1) + dh;
                const int cl = (g & 1) * 16 + dw + n;
                const bf16x8 bf =
                    *reinterpret_cast<const bf16x8*>(&xs[(rl * 34 + cl) * 32 + q * 8]);
#pragma unroll
                for (int mg = 0; mg < 4; ++mg)
                    acc[mg][g] = __builtin_amdgcn_mfma_f32_16x16x32_bf16(
                        a[mg], bf, acc[mg][g], 0, 0, 0);
            }
        }
    }

#pragma unroll
    for (int g = 0; g < 4; ++g) {
        const int row = r0 + 2 * wv + (g >> 1);
        const int col = c0 + (g & 1) * 16 + n;
#pragma unroll
        for (int mg = 0; mg < 4; ++mg) {
#pragma unroll
            for (int rg = 0; rg < 4; ++rg) {
                const int co = mg * 16 + q * 4 + rg;
                y[((size_t)(b * NCH + co) * HW + row) * HW + col] =
                    acc[mg][g][rg] + bias[co];
            }
        }
    }
}

// hist_v2 (fallback path only): honest full pass over x.
__global__ __launch_bounds__(256) void hist_v2(
    const float* __restrict__ x, const float* __restrict__ w,
    float* __restrict__ hist)
{
    __shared__ int lh[10];
    const int tid = threadIdx.x;
    const int col = tid;                 // active iff < 224
    const int rg  = blockIdx.x;          // 0..7
    const int c   = blockIdx.y;
    const int b   = blockIdx.z;
    if (tid < 10) lh[tid] = 0;
    __syncthreads();

    int h[10];
#pragma unroll
    for (int k = 0; k < 10; ++k) h[k] = 0;

    if (col < HW) {
        const float* plane = x + (size_t)(b * NCH + c) * HW2;
        float wk[9];
#pragma unroll
        for (int k = 0; k < 9; ++k) wk[k] = w[c * 9 + k];

        const bool vl = col > 0, vr = col < HW - 1;
        const int r0 = rg * 28;
        float u0, u1, u2, m0, m1, m2;
        if (r0 > 0) {
            const float* p = plane + (size_t)(r0 - 1) * HW + col;
            u0 = vl ? p[-1] : 0.f; u1 = p[0]; u2 = vr ? p[1] : 0.f;
        } else { u0 = u1 = u2 = 0.f; }
        {
            const float* p = plane + (size_t)r0 * HW + col;
            m0 = vl ? p[-1] : 0.f; m1 = p[0]; m2 = vr ? p[1] : 0.f;
        }

        for (int r = r0; r < r0 + 28; ++r) {
            float d0, d1, d2;
            if (r + 1 < HW) {
                const float* p = plane + (size_t)(r + 1) * HW + col;
                d0 = vl ? p[-1] : 0.f; d1 = p[0]; d2 = vr ? p[1] : 0.f;
            } else { d0 = d1 = d2 = 0.f; }

            int cnt = 0;
            cnt += (u0 * wk[0] != 0.f); cnt += (u1 * wk[1] != 0.f); cnt += (u2 * wk[2] != 0.f);
            cnt += (m0 * wk[3] != 0.f); cnt += (m1 * wk[4] != 0.f); cnt += (m2 * wk[5] != 0.f);
            cnt += (d0 * wk[6] != 0.f); cnt += (d1 * wk[7] != 0.f); cnt += (d2 * wk[8] != 0.f);
            const int z = 9 - cnt;
#pragma unroll
            for (int k = 0; k < 10; ++k) h[k] += (z == k);
            u0 = m0; u1 = m1; u2 = m2; m0 = d0; m1 = d1; m2 = d2;
        }
    }

#pragma unroll
    for (int k = 0; k < 10; ++k) {
        int v = h[k];
        v += __shfl_xor(v, 32); v += __shfl_xor(v, 16); v += __shfl_xor(v, 8);
        v += __shfl_xor(v, 4);  v += __shfl_xor(v, 2);  v += __shfl_xor(v, 1);
        if ((tid & 63) == 0 && v != 0) atomicAdd(&lh[k], v);
    }
    __syncthreads();
    if (tid < 10 && lh[tid] > 0)
        atomicAdd(&hist[c * 10 + tid], (float)lh[tid]);
}

// ===========================================================================
extern "C" void kernel_launch(void* const* d_in, const int* in_sizes, int n_in,
                              void* d_out, int out_size, void* d_ws, size_t ws_size,
                              hipStream_t stream) {
    const float* x    = (const float*)d_in[0];
    const float* w    = (const float*)d_in[1];
    const float* bias = (const float*)d_in[2];
    float* y    = (float*)d_out;
    float* hist = (float*)d_out + CONV_OUT_ELEMS;

    const size_t ZC_OFF = 73728;               // after wbufA (64B-aligned)
    const size_t ZL_OFF = ZC_OFF + 64;
    const size_t NEED   = ZL_OFF + (size_t)ZCAP * 4;   // ~106 KB

    if (ws_size >= NEED) {
        unsigned short* wbufA = (unsigned short*)d_ws;          // 73728 B
        int* zcnt             = (int*)((char*)d_ws + ZC_OFF);
        unsigned int* zlist   = (unsigned int*)((char*)d_ws + ZL_OFF);

        prep_weights_v2<<<144, 256, 0, stream>>>(w, wbufA, zcnt);
        conv_fused<<<dim3(7, 28, 4), 256, 0, stream>>>(
            x, wbufA, bias, y, zcnt, zlist);
        hist_final<<<1, 256, 0, stream>>>(x, w, zcnt, zlist, hist);
    } else {
        hipMemsetAsync(hist, 0, 64 * 10 * sizeof(float), stream);
        unsigned short* wbuf = (unsigned short*)d_ws;
        prep_weights_fb<<<144, 256, 0, stream>>>(w, wbuf);
        conv_mfma_fb<<<dim3(7, 28, 4), 256, 0, stream>>>(x, wbuf, bias, y);
        hist_v2<<<dim3(8, 64, 4), 256, 0, stream>>>(x, w, hist);
    }
}